// Round 3
// baseline (375.254 us; speedup 1.0000x reference)
//
#include <hip/hip_runtime.h>
#include <stdint.h>

static constexpr int NPTS  = 262144;
static constexpr int BATCH = 64;
static constexpr int BLKS1 = 32;   // blocks per batch, pass 1 (argmax y)
static constexpr int BLKS2 = 32;   // blocks per batch, pass 2 (dist argmax)

// ---- branchless packed argmax ----------------------------------------------
// key = (order_preserving_bits(value) << 32) | ~index
// max(key) == (max value; among ties the SMALLEST index) -> first-occurrence
// argmax, matching jnp.argmax. All keys > 0, so 0 is the identity element
// (ws slots are memset to 0 before use).

__device__ __forceinline__ uint32_t map_f32(float f) {
    uint32_t u = __float_as_uint(f);
    return (u & 0x80000000u) ? ~u : (u | 0x80000000u);
}

__device__ __forceinline__ uint64_t pack_key(uint32_t vbits, int i) {
    return ((uint64_t)vbits << 32) | (uint32_t)(~i);
}

__device__ __forceinline__ uint64_t umax64(uint64_t a, uint64_t b) {
    return a > b ? a : b;
}

// 256-thread block max of u64 keys; valid in thread 0
__device__ __forceinline__ uint64_t block_max_256(uint64_t k) {
    for (int off = 32; off > 0; off >>= 1)
        k = umax64(k, (uint64_t)__shfl_down((unsigned long long)k, off));
    __shared__ uint64_t s[4];
    int wid  = threadIdx.x >> 6;
    int lane = threadIdx.x & 63;
    if (lane == 0) s[wid] = k;
    __syncthreads();
    if (threadIdx.x == 0)
        for (int w = 1; w < 4; ++w) k = umax64(k, s[w]);
    return k;
}

// ---- pass 1: per-batch argmax over Y plane, result via atomicMax -----------
__global__ __launch_bounds__(256) void k_pass1(const float* __restrict__ xyz,
                                               uint64_t* __restrict__ key0) {
    int b   = blockIdx.x / BLKS1;
    int blk = blockIdx.x % BLKS1;
    const int chunk = NPTS / BLKS1;                       // 8192
    const float4* Y4 = (const float4*)(xyz + (size_t)b * 3 * NPTS + NPTS
                                       + (size_t)blk * chunk);
    int base = blk * chunk;
    uint64_t bk = 0;
#pragma unroll 4
    for (int j = threadIdx.x; j < chunk / 4; j += 256) {
        float4 y = Y4[j];
        int i0 = base + j * 4;
        bk = umax64(bk, pack_key(map_f32(y.x), i0));
        bk = umax64(bk, pack_key(map_f32(y.y), i0 + 1));
        bk = umax64(bk, pack_key(map_f32(y.z), i0 + 2));
        bk = umax64(bk, pack_key(map_f32(y.w), i0 + 3));
    }
    bk = block_max_256(bk);
    if (threadIdx.x == 0)
        atomicMax((unsigned long long*)&key0[b], (unsigned long long)bk);
}

// ---- pass 2: dist argmax; self-finalizing ----------------------------------
__global__ __launch_bounds__(256) void k_pass2(const float* __restrict__ xyz,
                                               const uint64_t* __restrict__ key0,
                                               uint64_t* __restrict__ key1,
                                               uint32_t* __restrict__ cnt,
                                               int* __restrict__ out) {
#pragma clang fp contract(off)
    int b   = blockIdx.x / BLKS2;
    int blk = blockIdx.x % BLKS2;
    const int chunk = NPTS / BLKS2;                       // 8192
    const float* bbase = xyz + (size_t)b * 3 * NPTS;

    // winner of pass 1 (coherent across the kernel boundary)
    uint64_t k0 = key0[b];
    int if0 = (int)(~(uint32_t)k0);
    // uniform-address gather: one request per wave, broadcast
    float cx = bbase[if0];
    float cy = bbase[NPTS + if0];
    float cz = bbase[2 * NPTS + if0];
    if (blk == 0 && threadIdx.x == 0) out[b * 2 + 0] = if0;

    const float* base = bbase + (size_t)blk * chunk;
    const float4* X4 = (const float4*)base;
    const float4* Y4 = (const float4*)(base + NPTS);
    const float4* Z4 = (const float4*)(base + 2 * NPTS);
    int ib = blk * chunk;
    uint64_t bk = 0;
#pragma unroll 4
    for (int j = threadIdx.x; j < chunk / 4; j += 256) {
        float4 x = X4[j], y = Y4[j], z = Z4[j];
        int i0 = ib + j * 4;
        {
            float dx = x.x - cx, dy = y.x - cy, dz = z.x - cz;
            float d = (dx * dx + dy * dy) + dz * dz;
            bk = umax64(bk, pack_key(__float_as_uint(d), i0));
        }
        {
            float dx = x.y - cx, dy = y.y - cy, dz = z.y - cz;
            float d = (dx * dx + dy * dy) + dz * dz;
            bk = umax64(bk, pack_key(__float_as_uint(d), i0 + 1));
        }
        {
            float dx = x.z - cx, dy = y.z - cy, dz = z.z - cz;
            float d = (dx * dx + dy * dy) + dz * dz;
            bk = umax64(bk, pack_key(__float_as_uint(d), i0 + 2));
        }
        {
            float dx = x.w - cx, dy = y.w - cy, dz = z.w - cz;
            float d = (dx * dx + dy * dy) + dz * dz;
            bk = umax64(bk, pack_key(__float_as_uint(d), i0 + 3));
        }
    }
    bk = block_max_256(bk);
    if (threadIdx.x == 0) {
        atomicMax((unsigned long long*)&key1[b], (unsigned long long)bk);
        __threadfence();
        uint32_t t = atomicAdd(&cnt[b], 1u);
        if (t == BLKS2 - 1) {
            // device-coherent readback of the final max
            uint64_t k1 = (uint64_t)atomicMax((unsigned long long*)&key1[b], 0ull);
            out[b * 2 + 1] = (int)(~(uint32_t)k1);
        }
    }
}

extern "C" void kernel_launch(void* const* d_in, const int* in_sizes, int n_in,
                              void* d_out, int out_size, void* d_ws, size_t ws_size,
                              hipStream_t stream) {
    const float* xyz = (const float*)d_in[0];
    int* out = (int*)d_out;
    char* ws = (char*)d_ws;
    // ws layout: key0[64] u64 @0 | key1[64] u64 @512 | cnt[64] u32 @1024
    uint64_t* key0 = (uint64_t*)ws;
    uint64_t* key1 = (uint64_t*)(ws + 512);
    uint32_t* cnt  = (uint32_t*)(ws + 1024);

    hipMemsetAsync(ws, 0, 2048, stream);   // zero atomic slots (ws is poisoned 0xAA)
    k_pass1<<<BATCH * BLKS1, 256, 0, stream>>>(xyz, key0);
    k_pass2<<<BATCH * BLKS2, 256, 0, stream>>>(xyz, key0, key1, cnt, out);
}

// Round 4
// 276.623 us; speedup vs baseline: 1.3566x; 1.3566x over previous
//
#include <hip/hip_runtime.h>
#include <stdint.h>

static constexpr int NPTS  = 262144;
static constexpr int BATCH = 64;
static constexpr int BLKS1 = 32;   // blocks per batch, pass 1 (argmax y)
static constexpr int BLKS2 = 32;   // blocks per batch, pass 2 (dist argmax)

// ---- branchless packed argmax ----------------------------------------------
// key = (order_preserving_bits(value) << 32) | ~index
// max(key) == (max value; among ties the SMALLEST index) -> first-occurrence
// argmax, matching jnp.argmax. All keys > 0, so 0 is the identity element
// (ws slots are memset to 0 before use).
// NOTE: no __threadfence anywhere — on gfx950 a device-scope fence is an L2
// writeback (multi-XCD coherence point is past the per-XCD L2); 2048 of them
// cost ~150 us (R3 lesson). Cross-kernel visibility comes from the implicit
// release/acquire at kernel boundaries instead.

__device__ __forceinline__ uint32_t map_f32(float f) {
    uint32_t u = __float_as_uint(f);
    return (u & 0x80000000u) ? ~u : (u | 0x80000000u);
}

__device__ __forceinline__ uint64_t pack_key(uint32_t vbits, int i) {
    return ((uint64_t)vbits << 32) | (uint32_t)(~i);
}

__device__ __forceinline__ uint64_t umax64(uint64_t a, uint64_t b) {
    return a > b ? a : b;
}

// 256-thread block max of u64 keys; valid in thread 0
__device__ __forceinline__ uint64_t block_max_256(uint64_t k) {
    for (int off = 32; off > 0; off >>= 1)
        k = umax64(k, (uint64_t)__shfl_down((unsigned long long)k, off));
    __shared__ uint64_t s[4];
    int wid  = threadIdx.x >> 6;
    int lane = threadIdx.x & 63;
    if (lane == 0) s[wid] = k;
    __syncthreads();
    if (threadIdx.x == 0)
        for (int w = 1; w < 4; ++w) k = umax64(k, s[w]);
    return k;
}

// ---- pass 1: per-batch argmax over Y plane, merged via relaxed atomicMax ---
__global__ __launch_bounds__(256) void k_pass1(const float* __restrict__ xyz,
                                               uint64_t* __restrict__ key0) {
    int b   = blockIdx.x / BLKS1;
    int blk = blockIdx.x % BLKS1;
    const int chunk = NPTS / BLKS1;                       // 8192
    const float4* Y4 = (const float4*)(xyz + (size_t)b * 3 * NPTS + NPTS
                                       + (size_t)blk * chunk);
    int base = blk * chunk;
    uint64_t bk = 0;
#pragma unroll 4
    for (int j = threadIdx.x; j < chunk / 4; j += 256) {
        float4 y = Y4[j];
        int i0 = base + j * 4;
        bk = umax64(bk, pack_key(map_f32(y.x), i0));
        bk = umax64(bk, pack_key(map_f32(y.y), i0 + 1));
        bk = umax64(bk, pack_key(map_f32(y.z), i0 + 2));
        bk = umax64(bk, pack_key(map_f32(y.w), i0 + 3));
    }
    bk = block_max_256(bk);
    if (threadIdx.x == 0)
        atomicMax((unsigned long long*)&key0[b], (unsigned long long)bk);
}

// ---- pass 2: dist argmax, merged via relaxed atomicMax ---------------------
__global__ __launch_bounds__(256) void k_pass2(const float* __restrict__ xyz,
                                               const uint64_t* __restrict__ key0,
                                               uint64_t* __restrict__ key1,
                                               int* __restrict__ out) {
#pragma clang fp contract(off)
    int b   = blockIdx.x / BLKS2;
    int blk = blockIdx.x % BLKS2;
    const int chunk = NPTS / BLKS2;                       // 8192
    const float* bbase = xyz + (size_t)b * 3 * NPTS;

    // pass-1 winner; visible via implicit kernel-boundary coherence
    uint64_t k0 = key0[b];
    int if0 = (int)(~(uint32_t)k0);
    // uniform-address gather: one request per wave, broadcast
    float cx = bbase[if0];
    float cy = bbase[NPTS + if0];
    float cz = bbase[2 * NPTS + if0];
    if (blk == 0 && threadIdx.x == 0) out[b * 2 + 0] = if0;

    const float* base = bbase + (size_t)blk * chunk;
    const float4* X4 = (const float4*)base;
    const float4* Y4 = (const float4*)(base + NPTS);
    const float4* Z4 = (const float4*)(base + 2 * NPTS);
    int ib = blk * chunk;
    uint64_t bk = 0;
#pragma unroll 4
    for (int j = threadIdx.x; j < chunk / 4; j += 256) {
        float4 x = X4[j], y = Y4[j], z = Z4[j];
        int i0 = ib + j * 4;
        // distances are >= 0, so raw float bits are already order-preserving
        {
            float dx = x.x - cx, dy = y.x - cy, dz = z.x - cz;
            float d = (dx * dx + dy * dy) + dz * dz;
            bk = umax64(bk, pack_key(__float_as_uint(d), i0));
        }
        {
            float dx = x.y - cx, dy = y.y - cy, dz = z.y - cz;
            float d = (dx * dx + dy * dy) + dz * dz;
            bk = umax64(bk, pack_key(__float_as_uint(d), i0 + 1));
        }
        {
            float dx = x.z - cx, dy = y.z - cy, dz = z.z - cz;
            float d = (dx * dx + dy * dy) + dz * dz;
            bk = umax64(bk, pack_key(__float_as_uint(d), i0 + 2));
        }
        {
            float dx = x.w - cx, dy = y.w - cy, dz = z.w - cz;
            float d = (dx * dx + dy * dy) + dz * dz;
            bk = umax64(bk, pack_key(__float_as_uint(d), i0 + 3));
        }
    }
    bk = block_max_256(bk);
    if (threadIdx.x == 0)
        atomicMax((unsigned long long*)&key1[b], (unsigned long long)bk);
}

// ---- finalize: one thread per batch writes out[2b+1] -----------------------
__global__ __launch_bounds__(64) void k_final(const uint64_t* __restrict__ key1,
                                              int* __restrict__ out) {
    int b = threadIdx.x;
    if (b < BATCH) out[b * 2 + 1] = (int)(~(uint32_t)key1[b]);
}

extern "C" void kernel_launch(void* const* d_in, const int* in_sizes, int n_in,
                              void* d_out, int out_size, void* d_ws, size_t ws_size,
                              hipStream_t stream) {
    const float* xyz = (const float*)d_in[0];
    int* out = (int*)d_out;
    char* ws = (char*)d_ws;
    // ws layout: key0[64] u64 @0 | key1[64] u64 @512
    uint64_t* key0 = (uint64_t*)ws;
    uint64_t* key1 = (uint64_t*)(ws + 512);

    hipMemsetAsync(ws, 0, 1024, stream);   // zero atomic slots (ws is poisoned 0xAA)
    k_pass1<<<BATCH * BLKS1, 256, 0, stream>>>(xyz, key0);
    k_pass2<<<BATCH * BLKS2, 256, 0, stream>>>(xyz, key0, key1, out);
    k_final<<<1, 64, 0, stream>>>(key1, out);
}

// Round 5
// 276.383 us; speedup vs baseline: 1.3577x; 1.0009x over previous
//
#include <hip/hip_runtime.h>
#include <stdint.h>

static constexpr int NPTS  = 262144;
static constexpr int BATCH = 64;
static constexpr int BLKS  = 32;   // blocks per batch, both passes

// ---- branchless packed argmax ----------------------------------------------
// key = (order_preserving_bits(value) << 32) | ~index
// max(key) == (max value; among ties the SMALLEST index) -> first-occurrence
// argmax, matching jnp.argmax.
// No atomics, no memset, no fences (R3 lesson: device-scope fences cost
// ~75ns/block serialized on gfx950 multi-XCD). Cross-kernel visibility of
// plain stores comes from the implicit release/acquire at kernel boundaries.

__device__ __forceinline__ uint32_t map_f32(float f) {
    uint32_t u = __float_as_uint(f);
    return (u & 0x80000000u) ? ~u : (u | 0x80000000u);
}

__device__ __forceinline__ uint64_t pack_key(uint32_t vbits, int i) {
    return ((uint64_t)vbits << 32) | (uint32_t)(~i);
}

__device__ __forceinline__ uint64_t umax64(uint64_t a, uint64_t b) {
    return a > b ? a : b;
}

// 256-thread block max of u64 keys; valid in thread 0
__device__ __forceinline__ uint64_t block_max_256(uint64_t k) {
    for (int off = 32; off > 0; off >>= 1)
        k = umax64(k, (uint64_t)__shfl_down((unsigned long long)k, off));
    __shared__ uint64_t s[4];
    int wid  = threadIdx.x >> 6;
    int lane = threadIdx.x & 63;
    if (lane == 0) s[wid] = k;
    __syncthreads();
    if (threadIdx.x == 0)
        for (int w = 1; w < 4; ++w) k = umax64(k, s[w]);
    return k;
}

// butterfly max within each 32-lane half; ALL lanes end with the half's max
__device__ __forceinline__ uint64_t half_wave_max(uint64_t k) {
    for (int off = 16; off > 0; off >>= 1)
        k = umax64(k, (uint64_t)__shfl_xor((unsigned long long)k, off));
    return k;
}

// ---- pass 1: per-batch argmax over Y plane -> plain-store partials ---------
__global__ __launch_bounds__(256) void k_pass1(const float* __restrict__ xyz,
                                               uint64_t* __restrict__ part1) {
    int b   = blockIdx.x / BLKS;
    int blk = blockIdx.x % BLKS;
    const int chunk = NPTS / BLKS;                        // 8192
    const float4* Y4 = (const float4*)(xyz + (size_t)b * 3 * NPTS + NPTS
                                       + (size_t)blk * chunk);
    int base = blk * chunk;
    uint64_t bk = 0;
#pragma unroll 4
    for (int j = threadIdx.x; j < chunk / 4; j += 256) {
        float4 y = Y4[j];
        int i0 = base + j * 4;
        bk = umax64(bk, pack_key(map_f32(y.x), i0));
        bk = umax64(bk, pack_key(map_f32(y.y), i0 + 1));
        bk = umax64(bk, pack_key(map_f32(y.z), i0 + 2));
        bk = umax64(bk, pack_key(map_f32(y.w), i0 + 3));
    }
    bk = block_max_256(bk);
    if (threadIdx.x == 0) part1[blockIdx.x] = bk;
}

// ---- pass 2: reduce pass-1 partials in prologue, dist argmax ---------------
__global__ __launch_bounds__(256) void k_pass2(const float* __restrict__ xyz,
                                               const uint64_t* __restrict__ part1,
                                               uint64_t* __restrict__ part2) {
#pragma clang fp contract(off)
    int b   = blockIdx.x / BLKS;
    int blk = blockIdx.x % BLKS;
    const int chunk = NPTS / BLKS;                        // 8192
    const float* bbase = xyz + (size_t)b * 3 * NPTS;

    // every thread redundantly reduces batch-b's 32 pass-1 partials (L2-hot,
    // 256 B) -> no separate merge kernel, no atomics
    uint64_t k0 = part1[b * BLKS + (threadIdx.x & 31)];
    k0 = half_wave_max(k0);
    int if0 = (int)(~(uint32_t)k0);
    // uniform-address gather: broadcast within wave
    float cx = bbase[if0];
    float cy = bbase[NPTS + if0];
    float cz = bbase[2 * NPTS + if0];

    const float* base = bbase + (size_t)blk * chunk;
    const float4* X4 = (const float4*)base;
    const float4* Y4 = (const float4*)(base + NPTS);
    const float4* Z4 = (const float4*)(base + 2 * NPTS);
    int ib = blk * chunk;
    uint64_t bk = 0;
#pragma unroll 4
    for (int j = threadIdx.x; j < chunk / 4; j += 256) {
        float4 x = X4[j], y = Y4[j], z = Z4[j];
        int i0 = ib + j * 4;
        // distances are >= 0, so raw float bits are already order-preserving
        {
            float dx = x.x - cx, dy = y.x - cy, dz = z.x - cz;
            float d = (dx * dx + dy * dy) + dz * dz;
            bk = umax64(bk, pack_key(__float_as_uint(d), i0));
        }
        {
            float dx = x.y - cx, dy = y.y - cy, dz = z.y - cz;
            float d = (dx * dx + dy * dy) + dz * dz;
            bk = umax64(bk, pack_key(__float_as_uint(d), i0 + 1));
        }
        {
            float dx = x.z - cx, dy = y.z - cy, dz = z.z - cz;
            float d = (dx * dx + dy * dy) + dz * dz;
            bk = umax64(bk, pack_key(__float_as_uint(d), i0 + 2));
        }
        {
            float dx = x.w - cx, dy = y.w - cy, dz = z.w - cz;
            float d = (dx * dx + dy * dy) + dz * dz;
            bk = umax64(bk, pack_key(__float_as_uint(d), i0 + 3));
        }
    }
    bk = block_max_256(bk);
    if (threadIdx.x == 0) part2[blockIdx.x] = bk;
}

// ---- finalize: one wave per batch reduces both partial sets ----------------
__global__ __launch_bounds__(64) void k_final(const uint64_t* __restrict__ part1,
                                              const uint64_t* __restrict__ part2,
                                              int* __restrict__ out) {
    int b = blockIdx.x;
    int t = threadIdx.x;
    uint64_t k = (t < 32) ? part1[b * BLKS + t] : part2[b * BLKS + (t - 32)];
    k = half_wave_max(k);
    if (t == 0)  out[b * 2 + 0] = (int)(~(uint32_t)k);
    if (t == 32) out[b * 2 + 1] = (int)(~(uint32_t)k);
}

extern "C" void kernel_launch(void* const* d_in, const int* in_sizes, int n_in,
                              void* d_out, int out_size, void* d_ws, size_t ws_size,
                              hipStream_t stream) {
    const float* xyz = (const float*)d_in[0];
    int* out = (int*)d_out;
    char* ws = (char*)d_ws;
    // ws layout: part1 [2048 u64 = 16 KB] | part2 [2048 u64]
    uint64_t* part1 = (uint64_t*)ws;
    uint64_t* part2 = (uint64_t*)(ws + 16384);

    k_pass1<<<BATCH * BLKS, 256, 0, stream>>>(xyz, part1);
    k_pass2<<<BATCH * BLKS, 256, 0, stream>>>(xyz, part1, part2);
    k_final<<<BATCH,        64,  0, stream>>>(part1, part2, out);
}

// Round 8
// 275.516 us; speedup vs baseline: 1.3620x; 1.0031x over previous
//
#include <hip/hip_runtime.h>
#include <stdint.h>

static constexpr int NPTS  = 262144;
static constexpr int BATCH = 64;
static constexpr int BLKS  = 32;   // blocks per batch, both passes

// ---- branchless packed argmax ----------------------------------------------
// key = (order_preserving_bits(value) << 32) | ~index
// max(key) == (max value; among ties the SMALLEST index) -> first-occurrence
// argmax, matching jnp.argmax.
// Coherence strategy (R3 lesson): NO __threadfence anywhere — a device-scope
// release fence is a per-block buffer_wbl2 L2-writeback on multi-XCD gfx950
// (~75ns serialized each; 2048 of them cost ~150us). Device-scope ATOMICS are
// globally coherent without flushes; ordering between two atomics from the
// same wave is enforced with a plain `s_waitcnt vmcnt(0)` (ack wait, not a
// cache op). Plain stores cross kernel boundaries via the implicit
// end-of-kernel release.

__device__ __forceinline__ uint32_t map_f32(float f) {
    uint32_t u = __float_as_uint(f);
    return (u & 0x80000000u) ? ~u : (u | 0x80000000u);
}

__device__ __forceinline__ uint64_t pack_key(uint32_t vbits, int i) {
    return ((uint64_t)vbits << 32) | (uint32_t)(~i);
}

__device__ __forceinline__ uint64_t umax64(uint64_t a, uint64_t b) {
    return a > b ? a : b;
}

// 256-thread block max of u64 keys; valid in thread 0
__device__ __forceinline__ uint64_t block_max_256(uint64_t k) {
    for (int off = 32; off > 0; off >>= 1)
        k = umax64(k, (uint64_t)__shfl_down((unsigned long long)k, off));
    __shared__ uint64_t s[4];
    int wid  = threadIdx.x >> 6;
    int lane = threadIdx.x & 63;
    if (lane == 0) s[wid] = k;
    __syncthreads();
    if (threadIdx.x == 0)
        for (int w = 1; w < 4; ++w) k = umax64(k, s[w]);
    return k;
}

// butterfly max within each 32-lane half; ALL lanes end with the half's max
__device__ __forceinline__ uint64_t half_wave_max(uint64_t k) {
    for (int off = 16; off > 0; off >>= 1)
        k = umax64(k, (uint64_t)__shfl_xor((unsigned long long)k, off));
    return k;
}

// ---- pass 1: per-batch argmax over Y plane -> plain-store partials ---------
// blk==0 blocks also zero pass-2's atomic slots (kernel-boundary visible),
// replacing a memset node.
__global__ __launch_bounds__(256) void k_pass1(const float* __restrict__ xyz,
                                               uint64_t* __restrict__ part1,
                                               uint64_t* __restrict__ key1,
                                               uint32_t* __restrict__ cnt1) {
    int b   = blockIdx.x / BLKS;
    int blk = blockIdx.x % BLKS;
    const int chunk = NPTS / BLKS;                        // 8192
    const float4* Y4 = (const float4*)(xyz + (size_t)b * 3 * NPTS + NPTS
                                       + (size_t)blk * chunk);
    int base = blk * chunk;
    uint64_t bk = 0;
#pragma unroll 4
    for (int j = threadIdx.x; j < chunk / 4; j += 256) {
        float4 y = Y4[j];
        int i0 = base + j * 4;
        bk = umax64(bk, pack_key(map_f32(y.x), i0));
        bk = umax64(bk, pack_key(map_f32(y.y), i0 + 1));
        bk = umax64(bk, pack_key(map_f32(y.z), i0 + 2));
        bk = umax64(bk, pack_key(map_f32(y.w), i0 + 3));
    }
    bk = block_max_256(bk);
    if (threadIdx.x == 0) {
        part1[blockIdx.x] = bk;
        if (blk == 0) { key1[b] = 0; cnt1[b] = 0; }
    }
}

// ---- pass 2: dist argmax, self-finalizing (no fence) -----------------------
__global__ __launch_bounds__(256) void k_pass2(const float* __restrict__ xyz,
                                               const uint64_t* __restrict__ part1,
                                               uint64_t* __restrict__ key1,
                                               uint32_t* __restrict__ cnt1,
                                               int* __restrict__ out) {
#pragma clang fp contract(off)
    int b   = blockIdx.x / BLKS;
    int blk = blockIdx.x % BLKS;
    const int chunk = NPTS / BLKS;                        // 8192
    const float* bbase = xyz + (size_t)b * 3 * NPTS;

    // every thread redundantly reduces batch-b's 32 pass-1 partials (256 B,
    // cache-hot) -> no merge kernel needed
    uint64_t k0 = part1[b * BLKS + (threadIdx.x & 31)];
    k0 = half_wave_max(k0);
    int if0 = (int)(~(uint32_t)k0);
    // uniform-address gather: broadcast within wave
    float cx = bbase[if0];
    float cy = bbase[NPTS + if0];
    float cz = bbase[2 * NPTS + if0];

    const float* base = bbase + (size_t)blk * chunk;
    const float4* X4 = (const float4*)base;
    const float4* Y4 = (const float4*)(base + NPTS);
    const float4* Z4 = (const float4*)(base + 2 * NPTS);
    int ib = blk * chunk;
    uint64_t bk = 0;
#pragma unroll 4
    for (int j = threadIdx.x; j < chunk / 4; j += 256) {
        float4 x = X4[j], y = Y4[j], z = Z4[j];
        int i0 = ib + j * 4;
        // distances are >= 0, so raw float bits are already order-preserving
        {
            float dx = x.x - cx, dy = y.x - cy, dz = z.x - cz;
            float d = (dx * dx + dy * dy) + dz * dz;
            bk = umax64(bk, pack_key(__float_as_uint(d), i0));
        }
        {
            float dx = x.y - cx, dy = y.y - cy, dz = z.y - cz;
            float d = (dx * dx + dy * dy) + dz * dz;
            bk = umax64(bk, pack_key(__float_as_uint(d), i0 + 1));
        }
        {
            float dx = x.z - cx, dy = y.z - cy, dz = z.z - cz;
            float d = (dx * dx + dy * dy) + dz * dz;
            bk = umax64(bk, pack_key(__float_as_uint(d), i0 + 2));
        }
        {
            float dx = x.w - cx, dy = y.w - cy, dz = z.w - cz;
            float d = (dx * dx + dy * dy) + dz * dz;
            bk = umax64(bk, pack_key(__float_as_uint(d), i0 + 3));
        }
    }
    bk = block_max_256(bk);
    if (threadIdx.x == 0) {
        if (blk == 0) out[b * 2 + 0] = if0;
        // relaxed device-scope atomic merge (coherent, no cache flush)
        atomicMax((unsigned long long*)&key1[b], (unsigned long long)bk);
        // order the merge before the arrival tick: wait for the atomic's ack
        // at the coherent point. NOT a cache op — cheap.
        asm volatile("s_waitcnt vmcnt(0)" ::: "memory");
        uint32_t old = atomicAdd(&cnt1[b], 1u);
        if (old == BLKS - 1) {
            // last arriver: all 32 merges complete; atomic read-back
            uint64_t k1 = (uint64_t)atomicMax((unsigned long long*)&key1[b], 0ull);
            out[b * 2 + 1] = (int)(~(uint32_t)k1);
        }
    }
}

extern "C" void kernel_launch(void* const* d_in, const int* in_sizes, int n_in,
                              void* d_out, int out_size, void* d_ws, size_t ws_size,
                              hipStream_t stream) {
    const float* xyz = (const float*)d_in[0];
    int* out = (int*)d_out;
    char* ws = (char*)d_ws;
    // ws layout: part1 [2048 u64 = 16 KB] | key1 [64 u64] | cnt1 [64 u32]
    uint64_t* part1 = (uint64_t*)ws;
    uint64_t* key1  = (uint64_t*)(ws + 16384);
    uint32_t* cnt1  = (uint32_t*)(ws + 16384 + 512);

    k_pass1<<<BATCH * BLKS, 256, 0, stream>>>(xyz, part1, key1, cnt1);
    k_pass2<<<BATCH * BLKS, 256, 0, stream>>>(xyz, part1, key1, cnt1, out);
}